// Round 1
// baseline (632.624 us; speedup 1.0000x reference)
//
#include <hip/hip_runtime.h>

typedef _Float16 half8 __attribute__((ext_vector_type(8)));
typedef float f32x4 __attribute__((ext_vector_type(4)));

constexpr int NB = 2048;        // windows (batch)
constexpr int CDIM = 384;       // channels
constexpr int NH = 12;          // heads
constexpr int MM = NB * 49;     // 100352 rows
constexpr int NTOT = 1152;      // qkv output cols
constexpr float SCALE = 0.17677669529663687f;  // 1/sqrt(32)

constexpr int XBLK = 37632;     // MM*CDIM/1024
constexpr int WBLK = 2304;      // (1152*384+384*384)/256

constexpr int QKV_BLOCKS = 9 * (MM / 128);   // 7056 = 8 * 882
constexpr int QKV_CHUNK  = QKV_BLOCKS / 8;   // 882
constexpr int PROJ_BLOCKS = 3 * (MM / 128);  // 2352 = 8 * 294
constexpr int PROJ_CHUNK  = PROJ_BLOCKS / 8; // 294

// async global->LDS, 16B per lane; lds ptr wave-uniform (HW adds lane*16)
__device__ __forceinline__ void async16(const void* g, void* l) {
    __builtin_amdgcn_global_load_lds((const __attribute__((address_space(1))) void*)g,
                                     (__attribute__((address_space(3))) void*)l, 16, 0, 0);
}

// ---------------- fused prep: convert x, transpose weights, build bias+mask table ----------------
// FT[w][h][k][q] (64x64 f32): rel_bias[h][q][k] + mask[w][q][k]; 0 outside 49x49.

__global__ __launch_bounds__(256) void prep(const float* __restrict__ x,
                                            const float* __restrict__ qkv_w,
                                            const float* __restrict__ proj_w,
                                            const int* __restrict__ rel_index,
                                            const float* __restrict__ rtable,
                                            const float* __restrict__ mask,
                                            _Float16* __restrict__ x_h,
                                            _Float16* __restrict__ qkvT,
                                            _Float16* __restrict__ projT,
                                            float* __restrict__ FT) {
    int bid = blockIdx.x;
    if (bid < XBLK) {
        size_t i = ((size_t)bid * 256 + threadIdx.x) * 4;
        float4 v = *(const float4*)(x + i);
        _Float16 h0 = (_Float16)v.x, h1 = (_Float16)v.y, h2 = (_Float16)v.z, h3 = (_Float16)v.w;
        _Float16* o = x_h + i;
        o[0] = h0; o[1] = h1; o[2] = h2; o[3] = h3;
    } else if (bid < XBLK + WBLK) {
        int i = (bid - XBLK) * 256 + threadIdx.x;
        if (i < 1152 * 384) {
            int n = i / 384, kk = i % 384;
            qkvT[i] = (_Float16)qkv_w[kk * 1152 + n];
        } else {
            int j = i - 1152 * 384;
            int n = j / 384, kk = j % 384;
            projT[j] = (_Float16)proj_w[kk * 384 + n];
        }
    } else {
        int wh = bid - XBLK - WBLK;     // 0..767
        int w = wh / 12, h = wh - w * 12;
        float* dst = FT + (size_t)wh * 4096;
        for (int idx = threadIdx.x; idx < 4096; idx += 256) {
            int k = idx >> 6, q = idx & 63;
            float v = 0.f;
            if (k < 49 && q < 49)
                v = rtable[rel_index[q * 49 + k] * NH + h] + mask[(size_t)w * 2401 + q * 49 + k];
            dst[idx] = v;
        }
    }
}

// ---------------- QKV GEMM: [100352,384] x [384,1152] -> C[100352][1152] f16 ----------------
// XCD-chunked block swizzle: each XCD owns 882 consecutive work-ids (= whole tm rows of 9
// tn-blocks), so the 98KB A-panel is fetched into one XCD's L2 once instead of 8 times.
// Epilogue stages the transpose in two 64-row halves -> LDS union = 32768B -> 5 blocks/CU.

__global__ __launch_bounds__(256) void gemm_qkv(const _Float16* __restrict__ A,
                                                const _Float16* __restrict__ Bt,
                                                const float* __restrict__ qkv_b,
                                                _Float16* __restrict__ C) {
    __shared__ union {
        struct { _Float16 A[128 * 64]; _Float16 B[128 * 64]; } st;
        _Float16 tile[64 * 136];
    } sm;
    _Float16* As = sm.st.A;
    _Float16* Bs = sm.st.B;

    const int K = 384;
    // bijective XCD swizzle (grid divisible by 8)
    const int bid = blockIdx.x;
    const int wid = (bid & 7) * QKV_CHUNK + (bid >> 3);
    const int tn = wid % 9, tm = wid / 9;
    const int t = threadIdx.x;
    const int wave = t >> 6, lane = t & 63;
    const int wm = (wave & 1) * 64, wn = (wave >> 1) * 64;
    const int quad = lane >> 4, l16 = lane & 15;
    const int rsub = lane >> 3, p = lane & 7;

    f32x4 acc[4][4] = {};
    const _Float16* Abase = A + (size_t)(tm * 128) * K;
    const _Float16* Bbase = Bt + (size_t)(tn * 128) * K;

    for (int k0 = 0; k0 < K; k0 += 64) {
        __syncthreads();
#pragma unroll
        for (int n = 0; n < 4; n++) {
            int ni = wave * 4 + n;
            int row = ni * 8 + rsub;
            int chunk = p ^ (row & 7);
            async16(Abase + (size_t)row * K + k0 + chunk * 8, (char*)As + ni * 1024);
            async16(Bbase + (size_t)row * K + k0 + chunk * 8, (char*)Bs + ni * 1024);
        }
        __syncthreads();
#pragma unroll
        for (int ks = 0; ks < 2; ks++) {
            half8 af[4], bfv[4];
#pragma unroll
            for (int i = 0; i < 4; i++)
                af[i] = *(const half8*)(&As[(wm + i * 16 + l16) * 64 + (((ks * 4 + quad) ^ (l16 & 7)) * 8)]);
#pragma unroll
            for (int j = 0; j < 4; j++)
                bfv[j] = *(const half8*)(&Bs[(wn + j * 16 + l16) * 64 + (((ks * 4 + quad) ^ (l16 & 7)) * 8)]);
#pragma unroll
            for (int i = 0; i < 4; i++)
#pragma unroll
                for (int j = 0; j < 4; j++)
                    acc[i][j] = __builtin_amdgcn_mfma_f32_16x16x32_f16(af[i], bfv[j], acc[i][j], 0, 0, 0);
        }
    }

    // ---- epilogue: bias (+q-scale) -> two 64-row half-tiles (f16, stride 136) -> 16B stores
    __syncthreads();                       // all LDS frag reads done before overwrite
    const int nbase = tn * 128, mbase = tm * 128;
    const float s = (tn < 3) ? SCALE : 1.f;
    float bj[4];
#pragma unroll
    for (int j = 0; j < 4; j++) bj[j] = qkv_b[nbase + wn + j * 16 + l16];

    const int rcol = (t & 15) * 8;
    const int rrow0 = t >> 4;

    for (int h = 0; h < 2; h++) {
        if ((wave & 1) == h) {
#pragma unroll
            for (int j = 0; j < 4; j++) {
                int n = wn + j * 16 + l16;
#pragma unroll
                for (int i = 0; i < 4; i++) {
#pragma unroll
                    for (int r = 0; r < 4; r++) {
                        int m = i * 16 + quad * 4 + r;     // local row within half
                        sm.tile[m * 136 + n] = (_Float16)((acc[i][j][r] + bj[j]) * s);
                    }
                }
            }
        }
        __syncthreads();
#pragma unroll
        for (int g = 0; g < 4; g++) {
            int row = g * 16 + rrow0;
            half8 val = *(const half8*)(&sm.tile[row * 136 + rcol]);
            *(half8*)(C + (size_t)(mbase + h * 64 + row) * NTOT + nbase + rcol) = val;
        }
        __syncthreads();
    }
}

// ---------------- attention: one WAVE per (b,h); no barriers ----------------

__global__ __launch_bounds__(256) void attn_kernel(const _Float16* __restrict__ C,
                                                   const float* __restrict__ FT,
                                                   _Float16* __restrict__ out) {
    __shared__ _Float16 Vt[4][32 * 72];   // per-wave V^T [d][l], l padded to 64 (zeros)
    __shared__ _Float16 Pb[4][16 * 72];   // per-wave P tile (f16)
    const int t = threadIdx.x;
    const int wave = t >> 6, lane = t & 63, quad = lane >> 4, l16 = lane & 15;
    const int gw = blockIdx.x * 4 + wave;           // global (b,h)
    const int b = gw / 12, h = gw - b * 12;

    const _Float16* qb = C + (size_t)b * 49 * NTOT + h * 32;
    const _Float16* kb = qb + 384;
    const _Float16* vb = qb + 768;
    const float* Fb = FT + ((size_t)((b & 63) * 12 + h)) * 4096;

    _Float16* vt = Vt[wave];
    // zero rows l=48..63 (one b128/wave), then stage V^T rows 0..48
    {
        int d = lane >> 1, seg = lane & 1;
        half8 z = {};
        *(half8*)(&vt[d * 72 + 48 + seg * 8]) = z;
    }
#pragma unroll
    for (int i2 = 0; i2 < 4; i2++) {
        int l = i2 * 16 + (lane >> 2);
        int d0 = (lane & 3) * 8;
        if (l < 49) {
            half8 v8 = *(const half8*)(vb + (size_t)l * NTOT + d0);
#pragma unroll
            for (int e = 0; e < 8; e++)
                vt[(d0 + e) * 72 + l] = v8[e];
        }
    }

    half8 bk[4];
#pragma unroll
    for (int j = 0; j < 4; j++) {
        int krow = j * 16 + l16; if (krow > 48) krow = 48;
        bk[j] = *(const half8*)(kb + (size_t)krow * NTOT + quad * 8);
    }
    half8 bv[2][2];
#pragma unroll
    for (int nt = 0; nt < 2; nt++)
#pragma unroll
        for (int ks = 0; ks < 2; ks++)
            bv[nt][ks] = *(const half8*)(&vt[(nt * 16 + l16) * 72 + ks * 32 + quad * 8]);

    _Float16* Pw = Pb[wave];
#pragma unroll
    for (int i = 0; i < 4; i++) {
        int qrow = i * 16 + l16; if (qrow > 48) qrow = 48;
        half8 aq = *(const half8*)(qb + (size_t)qrow * NTOT + quad * 8);

        f32x4 acc[4];
#pragma unroll
        for (int j = 0; j < 4; j++)
            acc[j] = *(const f32x4*)(Fb + (j * 16 + l16) * 64 + i * 16 + quad * 4);
#pragma unroll
        for (int j = 0; j < 4; j++)
            acc[j] = __builtin_amdgcn_mfma_f32_16x16x32_f16(aq, bk[j], acc[j], 0, 0, 0);

        if (l16 != 0) {                   // mask k = 48+l16 > 48
#pragma unroll
            for (int r = 0; r < 4; r++) acc[3][r] = -1e30f;
        }

        float rinv[4];
#pragma unroll
        for (int r = 0; r < 4; r++) {
            float m = fmaxf(fmaxf(acc[0][r], acc[1][r]), fmaxf(acc[2][r], acc[3][r]));
            m = fmaxf(m, __shfl_xor(m, 1, 64));
            m = fmaxf(m, __shfl_xor(m, 2, 64));
            m = fmaxf(m, __shfl_xor(m, 4, 64));
            m = fmaxf(m, __shfl_xor(m, 8, 64));
            float sum = 0.f;
#pragma unroll
            for (int j = 0; j < 4; j++) {
                float e = __expf(acc[j][r] - m);
                acc[j][r] = e;
                sum += e;
            }
            sum += __shfl_xor(sum, 1, 64);
            sum += __shfl_xor(sum, 2, 64);
            sum += __shfl_xor(sum, 4, 64);
            sum += __shfl_xor(sum, 8, 64);
            rinv[r] = 1.f / sum;
        }

        // C-layout -> A-layout via per-wave LDS (f16, stride 72); no barriers needed
#pragma unroll
        for (int j = 0; j < 4; j++)
#pragma unroll
            for (int r = 0; r < 4; r++)
                Pw[(quad * 4 + r) * 72 + j * 16 + l16] = (_Float16)acc[j][r];

        f32x4 oacc[2] = {};
#pragma unroll
        for (int ks = 0; ks < 2; ks++) {
            half8 ap = *(const half8*)(&Pw[l16 * 72 + ks * 32 + quad * 8]);
#pragma unroll
            for (int nt = 0; nt < 2; nt++)
                oacc[nt] = __builtin_amdgcn_mfma_f32_16x16x32_f16(ap, bv[nt][ks], oacc[nt], 0, 0, 0);
        }

#pragma unroll
        for (int nt = 0; nt < 2; nt++)
#pragma unroll
            for (int r = 0; r < 4; r++) {
                int q = i * 16 + quad * 4 + r;
                if (q < 49)
                    out[((size_t)b * 49 + q) * CDIM + h * 32 + nt * 16 + l16] =
                        (_Float16)(oacc[nt][r] * rinv[r]);
            }
    }
}

// ---------------- proj GEMM: [100352,384] x [384,384] + bias -> f32 out ----------------

__global__ __launch_bounds__(256) void gemm_proj(const _Float16* __restrict__ A,
                                                 const _Float16* __restrict__ Bt,
                                                 const float* __restrict__ proj_b,
                                                 float* __restrict__ out) {
    __shared__ _Float16 As[128 * 64];
    __shared__ _Float16 Bs[128 * 64];
    const int K = 384;
    const int bid = blockIdx.x;
    const int wid = (bid & 7) * PROJ_CHUNK + (bid >> 3);
    const int tn = wid % 3, tm = wid / 3;
    const int t = threadIdx.x;
    const int wave = t >> 6, lane = t & 63;
    const int wm = (wave & 1) * 64, wn = (wave >> 1) * 64;
    const int quad = lane >> 4, l16 = lane & 15;
    const int rsub = lane >> 3, p = lane & 7;

    f32x4 acc[4][4] = {};
    const _Float16* Abase = A + (size_t)(tm * 128) * K;
    const _Float16* Bbase = Bt + (size_t)(tn * 128) * K;

    for (int k0 = 0; k0 < K; k0 += 64) {
        __syncthreads();
#pragma unroll
        for (int n = 0; n < 4; n++) {
            int ni = wave * 4 + n;
            int row = ni * 8 + rsub;
            int chunk = p ^ (row & 7);
            async16(Abase + (size_t)row * K + k0 + chunk * 8, (char*)As + ni * 1024);
            async16(Bbase + (size_t)row * K + k0 + chunk * 8, (char*)Bs + ni * 1024);
        }
        __syncthreads();
#pragma unroll
        for (int ks = 0; ks < 2; ks++) {
            half8 af[4], bfv[4];
#pragma unroll
            for (int i = 0; i < 4; i++)
                af[i] = *(const half8*)(&As[(wm + i * 16 + l16) * 64 + (((ks * 4 + quad) ^ (l16 & 7)) * 8)]);
#pragma unroll
            for (int j = 0; j < 4; j++)
                bfv[j] = *(const half8*)(&Bs[(wn + j * 16 + l16) * 64 + (((ks * 4 + quad) ^ (l16 & 7)) * 8)]);
#pragma unroll
            for (int i = 0; i < 4; i++)
#pragma unroll
                for (int j = 0; j < 4; j++)
                    acc[i][j] = __builtin_amdgcn_mfma_f32_16x16x32_f16(af[i], bfv[j], acc[i][j], 0, 0, 0);
        }
    }

    const int mbase = tm * 128, nbase = tn * 128;
#pragma unroll
    for (int j = 0; j < 4; j++) {
        int n = nbase + wn + j * 16 + l16;
        float bias = proj_b[n];
#pragma unroll
        for (int i = 0; i < 4; i++) {
#pragma unroll
            for (int r = 0; r < 4; r++) {
                int m = mbase + wm + i * 16 + quad * 4 + r;
                out[(size_t)m * CDIM + n] = acc[i][j][r] + bias;
            }
        }
    }
}

// ---------------- launch ----------------

extern "C" void kernel_launch(void* const* d_in, const int* in_sizes, int n_in,
                              void* d_out, int out_size, void* d_ws, size_t ws_size,
                              hipStream_t stream) {
    const float* x        = (const float*)d_in[0];
    const int*   rel_idx  = (const int*)d_in[1];
    const float* amask    = (const float*)d_in[2];
    const float* qkv_w    = (const float*)d_in[3];
    const float* qkv_b    = (const float*)d_in[4];
    const float* rtable   = (const float*)d_in[5];
    const float* proj_w   = (const float*)d_in[6];
    const float* proj_b   = (const float*)d_in[7];
    float* out = (float*)d_out;

    char* w = (char*)d_ws;
    const size_t XB = (size_t)MM * CDIM * 2;        // 77,070,336
    const size_t CB = (size_t)MM * NTOT * 2;        // 231,211,008
    _Float16* x_h    = (_Float16*)w;
    _Float16* wqkvT  = (_Float16*)(w + XB);
    _Float16* wprojT = (_Float16*)(w + XB + 884736);
    _Float16* Cbuf   = (_Float16*)(w + XB + 884736 + 294912);
    float*    FT     = (float*)(w + XB + 884736 + 294912 + CB);   // 12,582,912
    _Float16* ao_h   = x_h;   // alias: x_h dead after gemm_qkv

    prep<<<XBLK + WBLK + 768, 256, 0, stream>>>(x, qkv_w, proj_w, rel_idx, rtable, amask,
                                                x_h, wqkvT, wprojT, FT);
    gemm_qkv<<<QKV_BLOCKS, 256, 0, stream>>>(x_h, wqkvT, qkv_b, Cbuf);
    attn_kernel<<<NB * NH / 4, 256, 0, stream>>>(Cbuf, FT, ao_h);
    gemm_proj<<<PROJ_BLOCKS, 256, 0, stream>>>(ao_h, wprojT, proj_b, out);
}